// Round 1
// baseline (144.666 us; speedup 1.0000x reference)
//
#include <hip/hip_runtime.h>
#include <math.h>

#define NFRAMES 8192   // B*T = 32*256
#define NS 8           // slots
#define NC 301         // classes incl EMPTY
#define EMPTYC 300

// Device-global scratch: fully rewritten every call (deterministic, no ws dependency)
__device__ float g_partial[5 * NFRAMES];
__device__ int g_maskmode;   // 0 = int32, 1 = byte-bool, 2 = float32

// ---------------------------------------------------------------------------
// Detect on-device layout of gt_mask (bool array from jax): scan first 64 KB.
// int32 0/1  -> all bytes at pos%4!=0 are zero.
// float 0/1  -> some word == 0x3f800000.
// bool bytes -> nonzero odd-position bytes, never the 1.0f pattern.
// All three hypotheses make the first 16384 words in-bounds.
// ---------------------------------------------------------------------------
__global__ __launch_bounds__(256) void detect_mask_kernel(const unsigned int* __restrict__ gm) {
    __shared__ int sOdd, sF1;
    int tid = threadIdx.x;
    if (tid == 0) { sOdd = 0; sF1 = 0; }
    __syncthreads();
    int lo = 0, lf = 0;
    for (int i = tid; i < (NFRAMES * NS) / 4; i += 256) {
        unsigned int w = gm[i];
        if (w & 0xFFFFFF00u) lo = 1;
        if (w == 0x3f800000u) lf = 1;
    }
    if (lo) atomicOr(&sOdd, 1);
    if (lf) atomicOr(&sF1, 1);
    __syncthreads();
    if (tid == 0) g_maskmode = (!sOdd) ? 0 : (sF1 ? 2 : 1);
}

// ---------------------------------------------------------------------------
// One wave per frame: softmax stats, cost matrix, exact JV Hungarian (lane 0,
// f64, faithful port of the reference), then all loss terms.
// ---------------------------------------------------------------------------
__global__ __launch_bounds__(64) void frame_kernel(
    const float* __restrict__ logits,   // [F, NS, NC]
    const float* __restrict__ doa,      // [F, NS, 3]
    const float* __restrict__ loud,     // [F, NS]
    const float* __restrict__ conf,     // [F, NS]
    const float* __restrict__ sce,      // [F, NS, 3]
    const int*   __restrict__ gcls,     // [F, NS]
    const float* __restrict__ gdoa,     // [F, NS, 3]
    const float* __restrict__ gloud,    // [F, NS]
    const void*  __restrict__ gmask)    // [F, NS] (format per g_maskmode)
{
    __shared__ float lg[NS * NC];          // staged logits
    __shared__ float Ms[NS], Zs[NS];       // per-slot max, sumexp
    __shared__ float dnv[NS][3], cpv[NS];  // normalized doa, sigmoid(conf)
    __shared__ int   actv[NS], gclv[NS];   // active gt slots, their classes
    __shared__ float gdn[NS][3];           // normalized gt doa
    __shared__ double Cm[NS][NS];          // cost matrix (reference orientation)
    __shared__ int   mtch[NS], tgts[NS], gidx[NS];
    __shared__ int   Gsh;
    // JV working arrays in LDS (lane 0 only) to avoid scratch spills
    __shared__ double u_[NS + 1], v_[NS + 1], minv_[NS + 1];
    __shared__ int    pj_[NS + 1], way_[NS + 1];
    __shared__ bool   used_[NS + 1];

    const int f = blockIdx.x;
    const int tid = threadIdx.x;

    // ---- stage logits (2408 floats = 602 float4, 16B aligned) ----
    {
        const float4* src = reinterpret_cast<const float4*>(logits + (size_t)f * NS * NC);
        float4* dst = reinterpret_cast<float4*>(lg);
        for (int i = tid; i < (NS * NC) / 4; i += 64) dst[i] = src[i];
    }
    __syncthreads();

    // ---- per-slot max & sumexp over 301 classes (8 lanes per slot) ----
    {
        int s = tid >> 3, g = tid & 7;
        float m = -INFINITY;
        for (int c = g; c < NC; c += 8) m = fmaxf(m, lg[s * NC + c]);
        for (int o = 1; o < 8; o <<= 1) m = fmaxf(m, __shfl_xor(m, o, 8));
        float z = 0.f;
        for (int c = g; c < NC; c += 8) z += expf(lg[s * NC + c] - m);
        for (int o = 1; o < 8; o <<= 1) z += __shfl_xor(z, o, 8);
        if (g == 0) { Ms[s] = m; Zs[s] = z; }
    }

    // ---- normalized pred doa + sigmoid(conf) ----
    if (tid < NS) {
        int s = tid;
        size_t b3 = ((size_t)f * NS + s) * 3;
        float x = doa[b3], y = doa[b3 + 1], w = doa[b3 + 2];
        float n = fmaxf(sqrtf(x * x + y * y + w * w), 1e-12f);
        dnv[s][0] = x / n; dnv[s][1] = y / n; dnv[s][2] = w / n;
        cpv[s] = 1.f / (1.f + expf(-conf[(size_t)f * NS + s]));
    }

    // ---- gather active gts (lane 0) ----
    if (tid == 0) {
        int mode = g_maskmode;
        int G = 0;
        for (int s = 0; s < NS; s++) {
            int idx = f * NS + s;
            bool on;
            if (mode == 0)      on = ((const int*)gmask)[idx] != 0;
            else if (mode == 1) on = ((const unsigned char*)gmask)[idx] != 0;
            else                on = ((const float*)gmask)[idx] != 0.f;
            if (on) {
                actv[G] = s; gclv[G] = gcls[idx];
                size_t b3 = (size_t)idx * 3;
                float x = gdoa[b3], y = gdoa[b3 + 1], w = gdoa[b3 + 2];
                float n = fmaxf(sqrtf(x * x + y * y + w * w), 1e-12f);
                gdn[G][0] = x / n; gdn[G][1] = y / n; gdn[G][2] = w / n;
                G++;
            }
        }
        Gsh = G;
    }
    __syncthreads();

    const int G = Gsh;

    // ---- cost matrix, float ops matching numpy, stored f64 in ref orientation ----
    {
        int p = tid >> 3, g = tid & 7;
        if (g < G) {
            int gc = gclv[g];
            float pr = expf(lg[p * NC + gc] - Ms[p]) / Zs[p];
            float dt = dnv[p][0] * gdn[g][0] + dnv[p][1] * gdn[g][1] + dnv[p][2] * gdn[g][2];
            float cv = -pr + (1.0f - dt) + 0.5f * (1.0f - cpv[p]);
            if (G < NS) Cm[g][p] = (double)cv;   // transposed: rows=gts, cols=preds
            else        Cm[p][g] = (double)cv;   // rows=preds, cols=gts
        }
    }
    __syncthreads();

    // ---- Jonker-Volgenant (exact port of reference _lsa), lane 0 ----
    if (tid == 0) {
        for (int s = 0; s < NS; s++) { mtch[s] = 0; tgts[s] = EMPTYC; gidx[s] = 0; }
        if (G > 0) {
            const int n = (G < NS) ? G : NS;
            const int m = NS;
            for (int j = 0; j <= m; j++) { u_[j] = 0.0; v_[j] = 0.0; pj_[j] = 0; }
            for (int i = 1; i <= n; i++) {
                pj_[0] = i; int j0 = 0;
                for (int j = 0; j <= m; j++) { minv_[j] = INFINITY; way_[j] = 0; used_[j] = false; }
                for (;;) {
                    used_[j0] = true;
                    int i0 = pj_[j0]; double delta = INFINITY; int j1 = 0;
                    for (int j = 1; j <= m; j++) if (!used_[j]) {
                        double cur = Cm[i0 - 1][j - 1] - u_[i0] - v_[j];
                        if (cur < minv_[j]) { minv_[j] = cur; way_[j] = j0; }
                        if (minv_[j] < delta) { delta = minv_[j]; j1 = j; }
                    }
                    for (int j = 0; j <= m; j++) {
                        if (used_[j]) { u_[pj_[j]] += delta; v_[j] -= delta; }
                        else          minv_[j] -= delta;
                    }
                    j0 = j1;
                    if (pj_[j0] == 0) break;
                }
                while (j0) { int j1 = way_[j0]; pj_[j0] = pj_[j1]; j0 = j1; }
            }
            for (int j = 1; j <= m; j++) if (pj_[j]) {
                int row = pj_[j] - 1, col = j - 1;
                int pred, gl;
                if (G < NS) { pred = col; gl = row; }
                else        { pred = row; gl = col; }
                mtch[pred] = 1; tgts[pred] = gclv[gl]; gidx[pred] = actv[gl];
            }
        }
    }
    __syncthreads();

    // ---- loss terms: one lane per slot, butterfly-reduce over 8 lanes ----
    if (tid < NS) {
        int s = tid;
        size_t base = (size_t)f * NS + s;
        float mf = (float)mtch[s];
        int tc = tgts[s];
        float ce = -(lg[s * NC + tc] - Ms[s] - logf(Zs[s]));
        float t1 = 1.f - expf(-ce);
        float fce = 0.25f * t1 * t1 * ce;

        int gi = gidx[s];
        size_t gb3 = ((size_t)f * NS + gi) * 3;
        float mdx = gdoa[gb3], mdy = gdoa[gb3 + 1], mdz = gdoa[gb3 + 2];
        float ml = gloud[(size_t)f * NS + gi];
        float dx = doa[base * 3], dy = doa[base * 3 + 1], dz = doa[base * 3 + 2];
        float num = dx * mdx + dy * mdy + dz * mdz;
        float den = fmaxf(sqrtf(dx * dx + dy * dy + dz * dz), 1e-8f) *
                    fmaxf(sqrtf(mdx * mdx + mdy * mdy + mdz * mdz), 1e-8f);
        float dterm = 1.f - num / den;

        float diff = loud[base] - ml;
        float ad = fabsf(diff);
        float sl1 = (ad < 1.f) ? 0.5f * diff * diff : (ad - 0.5f);

        float cf = conf[base];
        float sp = fmaxf(cf, 0.f) + log1pf(expf(-fabsf(cf)));   // softplus
        float bce = sp - cf * mf;

        float el = expf(ml * 0.05f);                            // exp(mloud/20)
        float e0 = sce[base * 3]     - mdx * el;
        float e1 = sce[base * 3 + 1] - mdy * el;
        float e2 = sce[base * 3 + 2] - mdz * el;
        float sq = (e0 * e0 + e1 * e1 + e2 * e2) * (1.f / 3.f);

        float c_m = fce * mf;
        float c_u = fce * (1.f - mf);
        float dsum = dterm * mf;
        float lsum = sl1 * mf;
        float qsum = sq * mf;
        float bsum = bce;
        for (int o = 1; o < 8; o <<= 1) {
            c_m  += __shfl_xor(c_m,  o, 8);
            c_u  += __shfl_xor(c_u,  o, 8);
            dsum += __shfl_xor(dsum, o, 8);
            lsum += __shfl_xor(lsum, o, 8);
            qsum += __shfl_xor(qsum, o, 8);
            bsum += __shfl_xor(bsum, o, 8);
        }
        if (s == 0) {
            float Gm = (float)G, Um = (float)(NS - G);
            float cls_fr  = (G > 0 ? c_m / Gm : 0.f) + (G < NS ? c_u / Um : 0.f);
            float doa_fr  = (G > 0) ? dsum / Gm : 0.f;
            float loud_fr = (G > 0) ? lsum / Gm : 0.f;
            float conf_fr = bsum * (1.f / 8.f);
            float sce_fr  = (G > 0) ? qsum / Gm : 0.f;
            g_partial[0 * NFRAMES + f] = cls_fr;
            g_partial[1 * NFRAMES + f] = doa_fr;
            g_partial[2 * NFRAMES + f] = loud_fr;
            g_partial[3 * NFRAMES + f] = conf_fr;
            g_partial[4 * NFRAMES + f] = sce_fr;
        }
    }
}

// ---------------------------------------------------------------------------
// Deterministic final reduction: 5 sums over 8192 frames -> weighted 6 outputs
// ---------------------------------------------------------------------------
__global__ __launch_bounds__(256) void reduce_kernel(float* __restrict__ out) {
    __shared__ float red[256];
    int tid = threadIdx.x;
    float acc[5];
    for (int k = 0; k < 5; k++) {
        float local = 0.f;
        for (int i = tid; i < NFRAMES; i += 256) local += g_partial[k * NFRAMES + i];
        red[tid] = local;
        __syncthreads();
        for (int off = 128; off > 0; off >>= 1) {
            if (tid < off) red[tid] += red[tid + off];
            __syncthreads();
        }
        acc[k] = red[0];
        __syncthreads();
    }
    if (tid == 0) {
        const float inv_norm = 1.f / (float)NFRAMES;
        float cls_l  = 1.0f * acc[0] * inv_norm;
        float doa_l  = 1.0f * acc[1] * inv_norm;
        float loud_l = 0.5f * acc[2] * inv_norm;
        float conf_l = 1.0f * acc[3] * inv_norm;
        float sce_l  = 0.3f * acc[4] * inv_norm;
        out[0] = cls_l; out[1] = doa_l; out[2] = loud_l;
        out[3] = conf_l; out[4] = sce_l;
        out[5] = cls_l + doa_l + loud_l + conf_l + sce_l;
    }
}

extern "C" void kernel_launch(void* const* d_in, const int* in_sizes, int n_in,
                              void* d_out, int out_size, void* d_ws, size_t ws_size,
                              hipStream_t stream) {
    const float* logits = (const float*)d_in[0];
    const float* doa    = (const float*)d_in[1];
    const float* loudn  = (const float*)d_in[2];
    const float* confi  = (const float*)d_in[3];
    const float* sce    = (const float*)d_in[4];
    const int*   gcls   = (const int*)d_in[5];
    const float* gdoa   = (const float*)d_in[6];
    const float* gloud  = (const float*)d_in[7];
    const void*  gmask  = d_in[8];
    float* out = (float*)d_out;

    detect_mask_kernel<<<1, 256, 0, stream>>>((const unsigned int*)gmask);
    frame_kernel<<<NFRAMES, 64, 0, stream>>>(logits, doa, loudn, confi, sce,
                                             gcls, gdoa, gloud, gmask);
    reduce_kernel<<<1, 256, 0, stream>>>(out);
}

// Round 2
// 95.092 us; speedup vs baseline: 1.5213x; 1.5213x over previous
//
#include <hip/hip_runtime.h>
#include <math.h>

#define NFRAMES 8192   // B*T = 32*256
#define NS 8
#define NC 301
#define EMPTYC 300

// Device-global scratch: fully rewritten every call (deterministic)
__device__ float g_partial[5 * NFRAMES];
__device__ int g_maskmode;   // 0 = int32, 1 = byte-bool, 2 = float32

// ---------------------------------------------------------------------------
// Detect on-device layout of gt_mask (unchanged from passing round)
// ---------------------------------------------------------------------------
__global__ __launch_bounds__(256) void detect_mask_kernel(const unsigned int* __restrict__ gm) {
    __shared__ int sOdd, sF1;
    int tid = threadIdx.x;
    if (tid == 0) { sOdd = 0; sF1 = 0; }
    __syncthreads();
    int lo = 0, lf = 0;
    for (int i = tid; i < (NFRAMES * NS) / 4; i += 256) {
        unsigned int w = gm[i];
        if (w & 0xFFFFFF00u) lo = 1;
        if (w == 0x3f800000u) lf = 1;
    }
    if (lo) atomicOr(&sOdd, 1);
    if (lf) atomicOr(&sF1, 1);
    __syncthreads();
    if (tid == 0) g_maskmode = (!sOdd) ? 0 : (sF1 ? 2 : 1);
}

// ---------------------------------------------------------------------------
// One wave per frame, 4 waves (4 frames) per block. NO LDS, NO barriers:
// everything via ballot/shuffle. Assignment solved by bitmask DP over 256
// masks held in 4 registers per lane (mask = lane | k<<6).
// ---------------------------------------------------------------------------
__global__ __launch_bounds__(256) void frame_kernel(
    const float* __restrict__ logits,   // [F, NS, NC]
    const float* __restrict__ doa,      // [F, NS, 3]
    const float* __restrict__ loud,     // [F, NS]
    const float* __restrict__ conf,     // [F, NS]
    const float* __restrict__ sce,      // [F, NS, 3]
    const int*   __restrict__ gcls,     // [F, NS]
    const float* __restrict__ gdoa,     // [F, NS, 3]
    const float* __restrict__ gloud,    // [F, NS]
    const void*  __restrict__ gmask)
{
    const int lane = threadIdx.x & 63;
    const int wv   = threadIdx.x >> 6;
    const int f    = blockIdx.x * 4 + wv;
    const int s    = lane >> 3;   // pred slot owned by this lane's 8-group
    const int g    = lane & 7;    // sub-index within group

    const float* fl = logits + (size_t)f * (NS * NC);

    // ---- softmax stats per slot: 8 lanes/slot, strided classes c = g+8k ----
    float m = -INFINITY;
    for (int k = 0; k < 38; k++) {
        int c = g + (k << 3);
        if (c < NC) m = fmaxf(m, fl[s * NC + c]);
    }
    m = fmaxf(m, __shfl_xor(m, 1, 8));
    m = fmaxf(m, __shfl_xor(m, 2, 8));
    m = fmaxf(m, __shfl_xor(m, 4, 8));
    float z = 0.f;
    for (int k = 0; k < 38; k++) {
        int c = g + (k << 3);
        if (c < NC) z += expf(fl[s * NC + c] - m);
    }
    z += __shfl_xor(z, 1, 8);
    z += __shfl_xor(z, 2, 8);
    z += __shfl_xor(z, 4, 8);

    // ---- active-gt discovery via ballot ----
    bool on = false;
    {
        int mode = g_maskmode;
        if (lane < 8) {
            int idx = f * NS + lane;
            if (mode == 0)      on = ((const int*)gmask)[idx] != 0;
            else if (mode == 1) on = ((const unsigned char*)gmask)[idx] != 0;
            else                on = ((const float*)gmask)[idx] != 0.f;
        }
    }
    unsigned long long bal = __ballot(on);
    const unsigned int actmask = (unsigned int)(bal & 0xFFull);
    const int G = __popc(actmask);

    // ---- lane g (< G) owns gt g: slot index, class, normalized doa ----
    int act_reg = 0, gcl_reg = 0;
    float gdx = 0.f, gdy = 0.f, gdz = 0.f;
    if (lane < G) {
        unsigned int mk = actmask;
        for (int t = 0; t < lane; t++) mk &= mk - 1;
        int slot = __ffs(mk) - 1;
        act_reg = slot;
        int idx = f * NS + slot;
        gcl_reg = gcls[idx];
        size_t b3 = (size_t)idx * 3;
        float x = gdoa[b3], y = gdoa[b3 + 1], zz = gdoa[b3 + 2];
        float n = fmaxf(sqrtf(x * x + y * y + zz * zz), 1e-12f);
        gdx = x / n; gdy = y / n; gdz = zz / n;
    }

    // ---- own-slot pred doa (normalized) + sigmoid(conf); redundant x8, cheap ----
    size_t sb3 = ((size_t)f * NS + s) * 3;
    float dxr = doa[sb3], dyr = doa[sb3 + 1], dzr = doa[sb3 + 2];
    float nn = fmaxf(sqrtf(dxr * dxr + dyr * dyr + dzr * dzr), 1e-12f);
    float dnx = dxr / nn, dny = dyr / nn, dnz = dzr / nn;
    float cp = 1.f / (1.f + expf(-conf[(size_t)f * NS + s]));

    // ---- cost for (pred s, gt g); lane holds C[g][s] ----
    int   gcg = __shfl(gcl_reg, g);
    float gx  = __shfl(gdx, g), gy = __shfl(gdy, g), gz = __shfl(gdz, g);
    float costreg = INFINITY;
    if (g < G) {
        float pr = expf(fl[s * NC + gcg] - m) / z;
        float dt = dnx * gx + dny * gy + dnz * gz;
        costreg = -pr + (1.f - dt) + 0.5f * (1.f - cp);
    }

    // ---- bitmask DP in registers: d[k] = dp[lane | k<<6] ----
    float d0 = (lane == 0) ? 0.f : INFINITY;
    float d1 = INFINITY, d2 = INFINITY, d3 = INFINITY;
    unsigned int par0 = 0, par1 = 0, par2 = 0, par3 = 0;

    for (int i = 0; i < G; i++) {
        float cc0 = __shfl(costreg,      i);
        float cc1 = __shfl(costreg,  8 + i);
        float cc2 = __shfl(costreg, 16 + i);
        float cc3 = __shfl(costreg, 24 + i);
        float cc4 = __shfl(costreg, 32 + i);
        float cc5 = __shfl(costreg, 40 + i);
        float cc6 = __shfl(costreg, 48 + i);
        float cc7 = __shfl(costreg, 56 + i);

        float n0, n1, n2, n3; int b0, b1, b2, b3i;

#define DP_LOW6(dk, bestv, bestb)                                                    \
        {                                                                            \
            float best = INFINITY; int bb = 0; float nb, cand;                       \
            nb = __shfl_xor(dk, 1);  cand = (lane & 1)  ? nb + cc0 : INFINITY; if (cand < best) { best = cand; bb = 0; } \
            nb = __shfl_xor(dk, 2);  cand = (lane & 2)  ? nb + cc1 : INFINITY; if (cand < best) { best = cand; bb = 1; } \
            nb = __shfl_xor(dk, 4);  cand = (lane & 4)  ? nb + cc2 : INFINITY; if (cand < best) { best = cand; bb = 2; } \
            nb = __shfl_xor(dk, 8);  cand = (lane & 8)  ? nb + cc3 : INFINITY; if (cand < best) { best = cand; bb = 3; } \
            nb = __shfl_xor(dk, 16); cand = (lane & 16) ? nb + cc4 : INFINITY; if (cand < best) { best = cand; bb = 4; } \
            nb = __shfl_xor(dk, 32); cand = (lane & 32) ? nb + cc5 : INFINITY; if (cand < best) { best = cand; bb = 5; } \
            bestv = best; bestb = bb;                                                \
        }

        DP_LOW6(d0, n0, b0)
        DP_LOW6(d1, n1, b1)
        DP_LOW6(d2, n2, b2)
        DP_LOW6(d3, n3, b3i)
#undef DP_LOW6
        // bit 6 (k&1): k=1 <- d0, k=3 <- d2
        { float cand = d0 + cc6; if (cand < n1) { n1 = cand; b1 = 6; } }
        { float cand = d2 + cc6; if (cand < n3) { n3 = cand; b3i = 6; } }
        // bit 7 (k&2): k=2 <- d0, k=3 <- d1
        { float cand = d0 + cc7; if (cand < n2) { n2 = cand; b2 = 7; } }
        { float cand = d1 + cc7; if (cand < n3) { n3 = cand; b3i = 7; } }

        d0 = n0; d1 = n1; d2 = n2; d3 = n3;
        int sh = 3 * i;
        par0 |= (unsigned)b0  << sh;
        par1 |= (unsigned)b1  << sh;
        par2 |= (unsigned)b2  << sh;
        par3 |= (unsigned)b3i << sh;
    }

    // ---- find argmin mask (uniform result in all lanes) + backtrack ----
    int mm_ = 0, mygt = 0;
    if (G > 0) {
        float v = d0; int bm = lane;
        if (d1 < v) { v = d1; bm = lane | 64; }
        if (d2 < v) { v = d2; bm = lane | 128; }
        if (d3 < v) { v = d3; bm = lane | 192; }
        for (int o = 1; o < 64; o <<= 1) {
            float ov = __shfl_xor(v, o);
            int   om = __shfl_xor(bm, o);
            if (ov < v || (ov == v && om < bm)) { v = ov; bm = om; }
        }
        int mask = bm;
        for (int i = G - 1; i >= 0; i--) {
            int owner = mask & 63, kk = mask >> 6;
            unsigned q0 = __shfl(par0, owner);
            unsigned q1 = __shfl(par1, owner);
            unsigned q2 = __shfl(par2, owner);
            unsigned q3 = __shfl(par3, owner);
            unsigned qv = (kk == 0) ? q0 : (kk == 1) ? q1 : (kk == 2) ? q2 : q3;
            int p = (qv >> (3 * i)) & 7;
            if (lane == p) { mm_ = 1; mygt = i; }
            mask ^= 1 << p;
        }
    }

    // ---- broadcast per-slot softmax stats + matched gt info (all lanes active) ----
    float M_s = __shfl(m, (lane & 7) << 3);
    float Z_s = __shfl(z, (lane & 7) << 3);
    int tgt_c  = __shfl(gcl_reg, mygt);
    int gidx_v = __shfl(act_reg, mygt);

    // ---- loss terms: lanes 0-7, one slot each ----
    if (lane < 8) {
        int ss = lane;
        size_t base = (size_t)f * NS + ss;
        float mf = (float)mm_;
        int tc = mm_ ? tgt_c : EMPTYC;
        float ce = -(fl[ss * NC + tc] - M_s - logf(Z_s));
        float t1 = 1.f - expf(-ce);
        float fce = 0.25f * t1 * t1 * ce;

        int gi = mm_ ? gidx_v : 0;
        size_t gb3 = ((size_t)f * NS + gi) * 3;
        float mdx = gdoa[gb3], mdy = gdoa[gb3 + 1], mdz = gdoa[gb3 + 2];
        float ml = gloud[(size_t)f * NS + gi];
        float dx = doa[base * 3], dy = doa[base * 3 + 1], dz = doa[base * 3 + 2];
        float num = dx * mdx + dy * mdy + dz * mdz;
        float den = fmaxf(sqrtf(dx * dx + dy * dy + dz * dz), 1e-8f) *
                    fmaxf(sqrtf(mdx * mdx + mdy * mdy + mdz * mdz), 1e-8f);
        float dterm = 1.f - num / den;

        float diff = loud[base] - ml;
        float ad = fabsf(diff);
        float sl1 = (ad < 1.f) ? 0.5f * diff * diff : (ad - 0.5f);

        float cf = conf[base];
        float sp = fmaxf(cf, 0.f) + log1pf(expf(-fabsf(cf)));
        float bce = sp - cf * mf;

        float el = expf(ml * 0.05f);
        float e0 = sce[base * 3]     - mdx * el;
        float e1 = sce[base * 3 + 1] - mdy * el;
        float e2 = sce[base * 3 + 2] - mdz * el;
        float sq = (e0 * e0 + e1 * e1 + e2 * e2) * (1.f / 3.f);

        float c_m  = fce * mf;
        float c_u  = fce * (1.f - mf);
        float dsum = dterm * mf;
        float lsum = sl1 * mf;
        float qsum = sq * mf;
        float bsum = bce;
        for (int o = 1; o < 8; o <<= 1) {
            c_m  += __shfl_xor(c_m,  o, 8);
            c_u  += __shfl_xor(c_u,  o, 8);
            dsum += __shfl_xor(dsum, o, 8);
            lsum += __shfl_xor(lsum, o, 8);
            qsum += __shfl_xor(qsum, o, 8);
            bsum += __shfl_xor(bsum, o, 8);
        }
        if (ss == 0) {
            float Gm = (float)G, Um = (float)(NS - G);
            float cls_fr  = (G > 0 ? c_m / Gm : 0.f) + (G < NS ? c_u / Um : 0.f);
            g_partial[0 * NFRAMES + f] = cls_fr;
            g_partial[1 * NFRAMES + f] = (G > 0) ? dsum / Gm : 0.f;
            g_partial[2 * NFRAMES + f] = (G > 0) ? lsum / Gm : 0.f;
            g_partial[3 * NFRAMES + f] = bsum * (1.f / 8.f);
            g_partial[4 * NFRAMES + f] = (G > 0) ? qsum / Gm : 0.f;
        }
    }
}

// ---------------------------------------------------------------------------
// Final reduction: 5 sums over 8192 frames -> weighted 6 outputs
// ---------------------------------------------------------------------------
__global__ __launch_bounds__(1024) void reduce_kernel(float* __restrict__ out) {
    __shared__ float red[1024];
    int tid = threadIdx.x;
    float acc[5];
#pragma unroll
    for (int k = 0; k < 5; k++) {
        float local = 0.f;
        for (int i = tid; i < NFRAMES; i += 1024) local += g_partial[k * NFRAMES + i];
        red[tid] = local;
        __syncthreads();
        for (int off = 512; off > 0; off >>= 1) {
            if (tid < off) red[tid] += red[tid + off];
            __syncthreads();
        }
        acc[k] = red[0];
        __syncthreads();
    }
    if (tid == 0) {
        const float inv_norm = 1.f / (float)NFRAMES;
        float cls_l  = 1.0f * acc[0] * inv_norm;
        float doa_l  = 1.0f * acc[1] * inv_norm;
        float loud_l = 0.5f * acc[2] * inv_norm;
        float conf_l = 1.0f * acc[3] * inv_norm;
        float sce_l  = 0.3f * acc[4] * inv_norm;
        out[0] = cls_l; out[1] = doa_l; out[2] = loud_l;
        out[3] = conf_l; out[4] = sce_l;
        out[5] = cls_l + doa_l + loud_l + conf_l + sce_l;
    }
}

extern "C" void kernel_launch(void* const* d_in, const int* in_sizes, int n_in,
                              void* d_out, int out_size, void* d_ws, size_t ws_size,
                              hipStream_t stream) {
    const float* logits = (const float*)d_in[0];
    const float* doa    = (const float*)d_in[1];
    const float* loudn  = (const float*)d_in[2];
    const float* confi  = (const float*)d_in[3];
    const float* sce    = (const float*)d_in[4];
    const int*   gcls   = (const int*)d_in[5];
    const float* gdoa   = (const float*)d_in[6];
    const float* gloud  = (const float*)d_in[7];
    const void*  gmask  = d_in[8];
    float* out = (float*)d_out;

    detect_mask_kernel<<<1, 256, 0, stream>>>((const unsigned int*)gmask);
    frame_kernel<<<NFRAMES / 4, 256, 0, stream>>>(logits, doa, loudn, confi, sce,
                                                  gcls, gdoa, gloud, gmask);
    reduce_kernel<<<1, 1024, 0, stream>>>(out);
}

// Round 3
// 61.981 us; speedup vs baseline: 2.3340x; 1.5342x over previous
//
#include <hip/hip_runtime.h>
#include <math.h>

#define NFRAMES 8192   // B*T = 32*256
#define NS 8
#define NC 301
#define EMPTYC 300

// Device-global scratch: fully rewritten every call (deterministic)
__device__ float g_partial[5 * NFRAMES];
__device__ int g_maskmode;   // 0 = int32, 1 = byte-bool, 2 = float32

// ---------------------------------------------------------------------------
// Detect on-device layout of gt_mask. Scan first 8 KB (2048 words) — with
// bernoulli(0.5) masks the three formats are statistically unmistakable.
// ---------------------------------------------------------------------------
__global__ __launch_bounds__(256) void detect_mask_kernel(const unsigned int* __restrict__ gm) {
    __shared__ int sOdd, sF1;
    int tid = threadIdx.x;
    if (tid == 0) { sOdd = 0; sF1 = 0; }
    __syncthreads();
    int lo = 0, lf = 0;
    for (int i = tid; i < 2048; i += 256) {
        unsigned int w = gm[i];
        if (w & 0xFFFFFF00u) lo = 1;
        if (w == 0x3f800000u) lf = 1;
    }
    if (lo) atomicOr(&sOdd, 1);
    if (lf) atomicOr(&sF1, 1);
    __syncthreads();
    if (tid == 0) g_maskmode = (!sOdd) ? 0 : (sF1 ? 2 : 1);
}

// ---------------------------------------------------------------------------
// One wave per frame, 4 waves per block. Logits staged to LDS via coalesced
// float4 (602 per frame); softmax/cost/CE read LDS. Matching = register
// bitmask DP over 256 masks (4 regs/lane), shuffles only.
// ---------------------------------------------------------------------------
__global__ __launch_bounds__(256) void frame_kernel(
    const float* __restrict__ logits,   // [F, NS, NC]
    const float* __restrict__ doa,      // [F, NS, 3]
    const float* __restrict__ loud,     // [F, NS]
    const float* __restrict__ conf,     // [F, NS]
    const float* __restrict__ sce,      // [F, NS, 3]
    const int*   __restrict__ gcls,     // [F, NS]
    const float* __restrict__ gdoa,     // [F, NS, 3]
    const float* __restrict__ gloud,    // [F, NS]
    const void*  __restrict__ gmask)
{
    __shared__ float lgs[4][NS * NC];   // 4 frames x 2408 floats = 38528 B

    const int lane = threadIdx.x & 63;
    const int wv   = threadIdx.x >> 6;
    const int f    = blockIdx.x * 4 + wv;
    const int s    = lane >> 3;   // pred slot owned by this lane's 8-group
    const int g    = lane & 7;    // sub-index within group

    // ---- stage logits: 602 float4, coalesced ----
    {
        const float4* src = reinterpret_cast<const float4*>(logits + (size_t)f * (NS * NC));
        float4* dst = reinterpret_cast<float4*>(&lgs[wv][0]);
#pragma unroll
        for (int k = 0; k < 10; k++) {
            int idx = lane + (k << 6);
            if (idx < 602) dst[idx] = src[idx];
        }
    }
    __syncthreads();

    const float* ls = &lgs[wv][s * NC];

    // ---- softmax stats per slot: 8 lanes/slot, strided classes c = g+8k ----
    float m = -INFINITY;
#pragma unroll
    for (int k = 0; k < 38; k++) {
        int c = g + (k << 3);
        if (c < NC) m = fmaxf(m, ls[c]);
    }
    m = fmaxf(m, __shfl_xor(m, 1, 8));
    m = fmaxf(m, __shfl_xor(m, 2, 8));
    m = fmaxf(m, __shfl_xor(m, 4, 8));
    float z = 0.f;
#pragma unroll
    for (int k = 0; k < 38; k++) {
        int c = g + (k << 3);
        if (c < NC) z += expf(ls[c] - m);
    }
    z += __shfl_xor(z, 1, 8);
    z += __shfl_xor(z, 2, 8);
    z += __shfl_xor(z, 4, 8);

    // ---- active-gt discovery via ballot ----
    bool on = false;
    {
        int mode = g_maskmode;
        if (lane < 8) {
            int idx = f * NS + lane;
            if (mode == 0)      on = ((const int*)gmask)[idx] != 0;
            else if (mode == 1) on = ((const unsigned char*)gmask)[idx] != 0;
            else                on = ((const float*)gmask)[idx] != 0.f;
        }
    }
    unsigned long long bal = __ballot(on);
    const unsigned int actmask = (unsigned int)(bal & 0xFFull);
    const int G = __popc(actmask);

    // ---- lane g (< G) owns gt g: slot index, class, normalized doa ----
    int act_reg = 0, gcl_reg = 0;
    float gdx = 0.f, gdy = 0.f, gdz = 0.f;
    if (lane < G) {
        unsigned int mk = actmask;
        for (int t = 0; t < lane; t++) mk &= mk - 1;
        int slot = __ffs(mk) - 1;
        act_reg = slot;
        int idx = f * NS + slot;
        gcl_reg = gcls[idx];
        size_t b3 = (size_t)idx * 3;
        float x = gdoa[b3], y = gdoa[b3 + 1], zz = gdoa[b3 + 2];
        float n = fmaxf(sqrtf(x * x + y * y + zz * zz), 1e-12f);
        gdx = x / n; gdy = y / n; gdz = zz / n;
    }

    // ---- own-slot pred doa (normalized) + sigmoid(conf) ----
    size_t sb3 = ((size_t)f * NS + s) * 3;
    float dxr = doa[sb3], dyr = doa[sb3 + 1], dzr = doa[sb3 + 2];
    float nn = fmaxf(sqrtf(dxr * dxr + dyr * dyr + dzr * dzr), 1e-12f);
    float dnx = dxr / nn, dny = dyr / nn, dnz = dzr / nn;
    float cp = 1.f / (1.f + expf(-conf[(size_t)f * NS + s]));

    // ---- cost for (pred s, gt g); lane holds C[g][s] ----
    int   gcg = __shfl(gcl_reg, g);
    float gx  = __shfl(gdx, g), gy = __shfl(gdy, g), gz = __shfl(gdz, g);
    float costreg = INFINITY;
    if (g < G) {
        float pr = expf(ls[gcg] - m) / z;
        float dt = dnx * gx + dny * gy + dnz * gz;
        costreg = -pr + (1.f - dt) + 0.5f * (1.f - cp);
    }

    // ---- bitmask DP in registers: d[k] = dp[lane | k<<6] ----
    float d0 = (lane == 0) ? 0.f : INFINITY;
    float d1 = INFINITY, d2 = INFINITY, d3 = INFINITY;
    unsigned int par0 = 0, par1 = 0, par2 = 0, par3 = 0;

    for (int i = 0; i < G; i++) {
        float cc0 = __shfl(costreg,      i);
        float cc1 = __shfl(costreg,  8 + i);
        float cc2 = __shfl(costreg, 16 + i);
        float cc3 = __shfl(costreg, 24 + i);
        float cc4 = __shfl(costreg, 32 + i);
        float cc5 = __shfl(costreg, 40 + i);
        float cc6 = __shfl(costreg, 48 + i);
        float cc7 = __shfl(costreg, 56 + i);

        float n0, n1, n2, n3; int b0, b1, b2, b3i;

#define DP_LOW6(dk, bestv, bestb)                                                    \
        {                                                                            \
            float best = INFINITY; int bb = 0; float nb, cand;                       \
            nb = __shfl_xor(dk, 1);  cand = (lane & 1)  ? nb + cc0 : INFINITY; if (cand < best) { best = cand; bb = 0; } \
            nb = __shfl_xor(dk, 2);  cand = (lane & 2)  ? nb + cc1 : INFINITY; if (cand < best) { best = cand; bb = 1; } \
            nb = __shfl_xor(dk, 4);  cand = (lane & 4)  ? nb + cc2 : INFINITY; if (cand < best) { best = cand; bb = 2; } \
            nb = __shfl_xor(dk, 8);  cand = (lane & 8)  ? nb + cc3 : INFINITY; if (cand < best) { best = cand; bb = 3; } \
            nb = __shfl_xor(dk, 16); cand = (lane & 16) ? nb + cc4 : INFINITY; if (cand < best) { best = cand; bb = 4; } \
            nb = __shfl_xor(dk, 32); cand = (lane & 32) ? nb + cc5 : INFINITY; if (cand < best) { best = cand; bb = 5; } \
            bestv = best; bestb = bb;                                                \
        }

        DP_LOW6(d0, n0, b0)
        DP_LOW6(d1, n1, b1)
        DP_LOW6(d2, n2, b2)
        DP_LOW6(d3, n3, b3i)
#undef DP_LOW6
        // bit 6 (k&1): k=1 <- d0, k=3 <- d2
        { float cand = d0 + cc6; if (cand < n1) { n1 = cand; b1 = 6; } }
        { float cand = d2 + cc6; if (cand < n3) { n3 = cand; b3i = 6; } }
        // bit 7 (k&2): k=2 <- d0, k=3 <- d1
        { float cand = d0 + cc7; if (cand < n2) { n2 = cand; b2 = 7; } }
        { float cand = d1 + cc7; if (cand < n3) { n3 = cand; b3i = 7; } }

        d0 = n0; d1 = n1; d2 = n2; d3 = n3;
        int sh = 3 * i;
        par0 |= (unsigned)b0  << sh;
        par1 |= (unsigned)b1  << sh;
        par2 |= (unsigned)b2  << sh;
        par3 |= (unsigned)b3i << sh;
    }

    // ---- find argmin mask (uniform in all lanes) + backtrack ----
    int mm_ = 0, mygt = 0;
    if (G > 0) {
        float v = d0; int bm = lane;
        if (d1 < v) { v = d1; bm = lane | 64; }
        if (d2 < v) { v = d2; bm = lane | 128; }
        if (d3 < v) { v = d3; bm = lane | 192; }
        for (int o = 1; o < 64; o <<= 1) {
            float ov = __shfl_xor(v, o);
            int   om = __shfl_xor(bm, o);
            if (ov < v || (ov == v && om < bm)) { v = ov; bm = om; }
        }
        int mask = bm;
        for (int i = G - 1; i >= 0; i--) {
            int owner = mask & 63, kk = mask >> 6;
            unsigned q0 = __shfl(par0, owner);
            unsigned q1 = __shfl(par1, owner);
            unsigned q2 = __shfl(par2, owner);
            unsigned q3 = __shfl(par3, owner);
            unsigned qv = (kk == 0) ? q0 : (kk == 1) ? q1 : (kk == 2) ? q2 : q3;
            int p = (qv >> (3 * i)) & 7;
            if (lane == p) { mm_ = 1; mygt = i; }
            mask ^= 1 << p;
        }
    }

    // ---- broadcast per-slot stats + matched gt info ----
    float M_s = __shfl(m, (lane & 7) << 3);
    float Z_s = __shfl(z, (lane & 7) << 3);
    int tgt_c  = __shfl(gcl_reg, mygt);
    int gidx_v = __shfl(act_reg, mygt);

    // ---- loss terms: lanes 0-7, one slot each ----
    if (lane < 8) {
        int ss = lane;
        size_t base = (size_t)f * NS + ss;
        float mf = (float)mm_;
        int tc = mm_ ? tgt_c : EMPTYC;
        float ce = -(lgs[wv][ss * NC + tc] - M_s - logf(Z_s));
        float t1 = 1.f - expf(-ce);
        float fce = 0.25f * t1 * t1 * ce;

        int gi = mm_ ? gidx_v : 0;
        size_t gb3 = ((size_t)f * NS + gi) * 3;
        float mdx = gdoa[gb3], mdy = gdoa[gb3 + 1], mdz = gdoa[gb3 + 2];
        float ml = gloud[(size_t)f * NS + gi];
        float dx = doa[base * 3], dy = doa[base * 3 + 1], dz = doa[base * 3 + 2];
        float num = dx * mdx + dy * mdy + dz * mdz;
        float den = fmaxf(sqrtf(dx * dx + dy * dy + dz * dz), 1e-8f) *
                    fmaxf(sqrtf(mdx * mdx + mdy * mdy + mdz * mdz), 1e-8f);
        float dterm = 1.f - num / den;

        float diff = loud[base] - ml;
        float ad = fabsf(diff);
        float sl1 = (ad < 1.f) ? 0.5f * diff * diff : (ad - 0.5f);

        float cf = conf[base];
        float sp = fmaxf(cf, 0.f) + log1pf(expf(-fabsf(cf)));
        float bce = sp - cf * mf;

        float el = expf(ml * 0.05f);
        float e0 = sce[base * 3]     - mdx * el;
        float e1 = sce[base * 3 + 1] - mdy * el;
        float e2 = sce[base * 3 + 2] - mdz * el;
        float sq = (e0 * e0 + e1 * e1 + e2 * e2) * (1.f / 3.f);

        float c_m  = fce * mf;
        float c_u  = fce * (1.f - mf);
        float dsum = dterm * mf;
        float lsum = sl1 * mf;
        float qsum = sq * mf;
        float bsum = bce;
        for (int o = 1; o < 8; o <<= 1) {
            c_m  += __shfl_xor(c_m,  o, 8);
            c_u  += __shfl_xor(c_u,  o, 8);
            dsum += __shfl_xor(dsum, o, 8);
            lsum += __shfl_xor(lsum, o, 8);
            qsum += __shfl_xor(qsum, o, 8);
            bsum += __shfl_xor(bsum, o, 8);
        }
        if (ss == 0) {
            float Gm = (float)G, Um = (float)(NS - G);
            float cls_fr  = (G > 0 ? c_m / Gm : 0.f) + (G < NS ? c_u / Um : 0.f);
            g_partial[0 * NFRAMES + f] = cls_fr;
            g_partial[1 * NFRAMES + f] = (G > 0) ? dsum / Gm : 0.f;
            g_partial[2 * NFRAMES + f] = (G > 0) ? lsum / Gm : 0.f;
            g_partial[3 * NFRAMES + f] = bsum * (1.f / 8.f);
            g_partial[4 * NFRAMES + f] = (G > 0) ? qsum / Gm : 0.f;
        }
    }
}

// ---------------------------------------------------------------------------
// Final reduction: 5 sums over 8192 frames -> weighted 6 outputs
// ---------------------------------------------------------------------------
__global__ __launch_bounds__(1024) void reduce_kernel(float* __restrict__ out) {
    __shared__ float red[1024];
    int tid = threadIdx.x;
    float acc[5];
#pragma unroll
    for (int k = 0; k < 5; k++) {
        float local = 0.f;
        for (int i = tid; i < NFRAMES; i += 1024) local += g_partial[k * NFRAMES + i];
        red[tid] = local;
        __syncthreads();
        for (int off = 512; off > 0; off >>= 1) {
            if (tid < off) red[tid] += red[tid + off];
            __syncthreads();
        }
        acc[k] = red[0];
        __syncthreads();
    }
    if (tid == 0) {
        const float inv_norm = 1.f / (float)NFRAMES;
        float cls_l  = 1.0f * acc[0] * inv_norm;
        float doa_l  = 1.0f * acc[1] * inv_norm;
        float loud_l = 0.5f * acc[2] * inv_norm;
        float conf_l = 1.0f * acc[3] * inv_norm;
        float sce_l  = 0.3f * acc[4] * inv_norm;
        out[0] = cls_l; out[1] = doa_l; out[2] = loud_l;
        out[3] = conf_l; out[4] = sce_l;
        out[5] = cls_l + doa_l + loud_l + conf_l + sce_l;
    }
}

extern "C" void kernel_launch(void* const* d_in, const int* in_sizes, int n_in,
                              void* d_out, int out_size, void* d_ws, size_t ws_size,
                              hipStream_t stream) {
    const float* logits = (const float*)d_in[0];
    const float* doa    = (const float*)d_in[1];
    const float* loudn  = (const float*)d_in[2];
    const float* confi  = (const float*)d_in[3];
    const float* sce    = (const float*)d_in[4];
    const int*   gcls   = (const int*)d_in[5];
    const float* gdoa   = (const float*)d_in[6];
    const float* gloud  = (const float*)d_in[7];
    const void*  gmask  = d_in[8];
    float* out = (float*)d_out;

    detect_mask_kernel<<<1, 256, 0, stream>>>((const unsigned int*)gmask);
    frame_kernel<<<NFRAMES / 4, 256, 0, stream>>>(logits, doa, loudn, confi, sce,
                                                  gcls, gdoa, gloud, gmask);
    reduce_kernel<<<1, 1024, 0, stream>>>(out);
}